// Round 7
// baseline (322.034 us; speedup 1.0000x reference)
//
#include <hip/hip_runtime.h>
#include <hip/hip_bf16.h>

// Problem constants (B,C,H,W = 4,512,64,64; A=64; N=H*W=4096)
constexpr int BB = 4;
constexpr int C  = 512;
constexpr int A  = 64;
constexpr int N  = 4096;

typedef __attribute__((ext_vector_type(8))) short s16x8;   // 8 bf16 (4 VGPRs)
typedef __attribute__((ext_vector_type(4))) float f32x4;   // 4 fp32 acc

#define MFMA_16x16x32_BF16(a, b, c) __builtin_amdgcn_mfma_f32_16x16x32_bf16((a), (b), (c), 0, 0, 0)

typedef __attribute__((address_space(3))) unsigned int lds_u32_t;
typedef const __attribute__((address_space(1))) unsigned int glb_u32_t;

__device__ __forceinline__ void gl2lds16(const void* g, void* l) {
    // async global->LDS, 16B/lane; LDS dest = wave-uniform base + lane*16
    __builtin_amdgcn_global_load_lds((glb_u32_t*)g, (lds_u32_t*)l, 16, 0, 0);
}

// Issue-pinned 16B global load (volatile asm: not sinkable, dst forced live).
// Caller owns s_waitcnt vmcnt(N) before consumption.
#define GLOAD(dst, base, off)                                                  \
    asm volatile("global_load_dwordx4 %0, %1, %2"                              \
                 : "=v"(dst) : "v"(off), "s"(base))

// ---------------------------------------------------------------------------
// K0a: transpose + fp32->bf16. src [z][K][M] fp32 -> dst [z][M][K] bf16.
__global__ __launch_bounds__(256) void k_trans(const float* __restrict__ src,
                                               __hip_bfloat16* __restrict__ dst,
                                               int K, int M) {
    __shared__ __hip_bfloat16 Ls[64][66];
    int m0 = blockIdx.x << 6, k0 = blockIdx.y << 6;
    size_t bo = (size_t)blockIdx.z * K * M;
    int t = threadIdx.x;
    int lm = t & 63, g = t >> 6;
    #pragma unroll
    for (int j = 0; j < 16; ++j) {
        int kk = j * 4 + g;
        Ls[kk][lm] = __float2bfloat16(src[bo + (size_t)(k0 + kk) * M + m0 + lm]);
    }
    __syncthreads();
    #pragma unroll
    for (int j = 0; j < 16; ++j) {
        int mm = j * 4 + g;
        dst[bo + (size_t)(m0 + mm) * K + k0 + lm] = Ls[lm][mm];
    }
}

// ---------------------------------------------------------------------------
// K0b: transpose + hi/lo bf16 split. src [z][K][M] fp32 -> dhi/dlo [z][M][K].
__global__ __launch_bounds__(256) void k_trans2(const float* __restrict__ src,
                                                __hip_bfloat16* __restrict__ dhi,
                                                __hip_bfloat16* __restrict__ dlo,
                                                int K, int M) {
    __shared__ float Ls[64][65];
    int m0 = blockIdx.x << 6, k0 = blockIdx.y << 6;
    size_t bo = (size_t)blockIdx.z * K * M;
    int t = threadIdx.x;
    int lm = t & 63, g = t >> 6;
    #pragma unroll
    for (int j = 0; j < 16; ++j) {
        int kk = j * 4 + g;
        Ls[kk][lm] = src[bo + (size_t)(k0 + kk) * M + m0 + lm];
    }
    __syncthreads();
    #pragma unroll
    for (int j = 0; j < 16; ++j) {
        int mm = j * 4 + g;
        float v = Ls[lm][mm];
        __hip_bfloat16 h = __float2bfloat16(v);
        size_t idx = bo + (size_t)(m0 + mm) * K + k0 + lm;
        dhi[idx] = h;
        dlo[idx] = __float2bfloat16(v - __bfloat162float(h));
    }
}

// ---------------------------------------------------------------------------
// K1 v2 (k_fgm): f,g convs as ONE split-precision MFMA GEMM.
__global__ __launch_bounds__(256) void k_fgm(const __hip_bfloat16* __restrict__ XThi, const __hip_bfloat16* __restrict__ XTlo,
                                             const __hip_bfloat16* __restrict__ WfThi, const __hip_bfloat16* __restrict__ WfTlo,
                                             const __hip_bfloat16* __restrict__ WgThi, const __hip_bfloat16* __restrict__ WgTlo,
                                             const float* __restrict__ bfv, const float* __restrict__ bgv,
                                             __hip_bfloat16* __restrict__ FFhi, __hip_bfloat16* __restrict__ FFlo,
                                             __hip_bfloat16* __restrict__ GFhi, __hip_bfloat16* __restrict__ GFlo) {
    __shared__ __align__(16) __hip_bfloat16 Ah[64 * 32], Al[64 * 32];    // 4+4 KB
    __shared__ __align__(16) __hip_bfloat16 Bh[128 * 32], Bl[128 * 32];  // 8+8 KB
    int r0 = blockIdx.x << 6;           // global row base (b*N+n), 0..16320
    int t = threadIdx.x;
    int w = t >> 6, l = t & 63;
    int ln15 = l & 15, quad = l >> 4;
    int mh = w & 1, nh = w >> 1;

    f32x4 acc[2][4];
    #pragma unroll
    for (int mi = 0; mi < 2; ++mi)
        #pragma unroll
        for (int ni = 0; ni < 4; ++ni) acc[mi][ni] = (f32x4){0.f, 0.f, 0.f, 0.f};

    for (int kt = 0; kt < C; kt += 32) {
        {   // A tiles: 64 rows x 32 k, hi+lo, XOR-rotation swizzled segs
            int row = t >> 2, seg = t & 3;
            int gseg = (seg - (row >> 1)) & 3;
            size_t go = (size_t)(r0 + row) * C + kt + gseg * 8;
            gl2lds16(XThi + go, &Ah[t * 8]);
            gl2lds16(XTlo + go, &Al[t * 8]);
        }
        #pragma unroll
        for (int j = 0; j < 2; ++j) {   // B tiles: rows 0-63 = WfT, 64-127 = WgT
            int i = j * 256 + t;
            int row = i >> 2, seg = i & 3;
            int gseg = (seg - (row >> 1)) & 3;
            size_t go = (size_t)(row & 63) * C + kt + gseg * 8;
            const __hip_bfloat16* bh = j ? WgThi : WfThi;
            const __hip_bfloat16* bl = j ? WgTlo : WfTlo;
            gl2lds16(bh + go, &Bh[i * 8]);
            gl2lds16(bl + go, &Bl[i * 8]);
        }
        __syncthreads();
        s16x8 afh[2], afl[2], bfh[4], bfl[4];
        #pragma unroll
        for (int mi = 0; mi < 2; ++mi) {
            int row = mh * 32 + mi * 16 + ln15;
            int sw = ((quad + (row >> 1)) & 3) << 3;
            afh[mi] = *(const s16x8*)&Ah[row * 32 + sw];
            afl[mi] = *(const s16x8*)&Al[row * 32 + sw];
        }
        #pragma unroll
        for (int ni = 0; ni < 4; ++ni) {
            int row = nh * 64 + ni * 16 + ln15;
            int sw = ((quad + (row >> 1)) & 3) << 3;
            bfh[ni] = *(const s16x8*)&Bh[row * 32 + sw];
            bfl[ni] = *(const s16x8*)&Bl[row * 32 + sw];
        }
        #pragma unroll
        for (int mi = 0; mi < 2; ++mi)
            #pragma unroll
            for (int ni = 0; ni < 4; ++ni) {
                acc[mi][ni] = MFMA_16x16x32_BF16(afh[mi], bfh[ni], acc[mi][ni]);
                acc[mi][ni] = MFMA_16x16x32_BF16(afl[mi], bfh[ni], acc[mi][ni]);
                acc[mi][ni] = MFMA_16x16x32_BF16(afh[mi], bfl[ni], acc[mi][ni]);
            }
        __syncthreads();
    }

    #pragma unroll
    for (int mi = 0; mi < 2; ++mi) {
        #pragma unroll
        for (int r = 0; r < 4; ++r) {
            size_t grow = (size_t)(r0 + mh * 32 + mi * 16 + quad * 4 + r) * A;
            #pragma unroll
            for (int ni = 0; ni < 4; ++ni) {
                int col = nh * 64 + ni * 16 + ln15;     // nh selects f vs g (wave-uniform)
                if (col < A) {
                    float v = acc[mi][ni][r] + bfv[col];
                    __hip_bfloat16 h = __float2bfloat16(v);
                    FFhi[grow + col] = h;
                    FFlo[grow + col] = __float2bfloat16(v - __bfloat162float(h));
                } else {
                    int a = col - A;
                    float v = acc[mi][ni][r] + bgv[a];
                    __hip_bfloat16 h = __float2bfloat16(v);
                    GFhi[grow + a] = h;
                    GFlo[grow + a] = __float2bfloat16(v - __bfloat162float(h));
                }
            }
        }
    }
}

// ---------------------------------------------------------------------------
// K2: h conv as bf16 MFMA GEMM. HFT[c][n] = sum_k WhT[c][k]*XT[b][n][k] + bh[c].
__global__ __launch_bounds__(256) void k_hm(const __hip_bfloat16* __restrict__ WhT,
                                            const __hip_bfloat16* __restrict__ XT,
                                            const float* __restrict__ bhv,
                                            __hip_bfloat16* __restrict__ HFT) {
    __shared__ __align__(16) __hip_bfloat16 As[128 * 32];
    __shared__ __align__(16) __hip_bfloat16 Bs[128 * 32];
    int b  = blockIdx.z;
    int c0 = blockIdx.x << 7;
    int n0 = blockIdx.y << 7;
    int t = threadIdx.x;
    int w = t >> 6, l = t & 63;
    int ln15 = l & 15, quad = l >> 4;
    int mc = (w >> 1) << 6, nn = (w & 1) << 6;

    const __hip_bfloat16* Bb = XT + (size_t)b * N * C;   // [4096, 512]

    f32x4 acc[4][4];
    #pragma unroll
    for (int mi = 0; mi < 4; ++mi)
        #pragma unroll
        for (int ni = 0; ni < 4; ++ni) acc[mi][ni] = (f32x4){0.f, 0.f, 0.f, 0.f};

    for (int kt = 0; kt < C; kt += 32) {
        #pragma unroll
        for (int j = 0; j < 2; ++j) {
            int i = j * 256 + t;
            int row = i >> 2, seg = i & 3;
            int gseg = (seg - (row >> 1)) & 3;
            gl2lds16(WhT + ((size_t)(c0 + row) * C + kt + gseg * 8), &As[i * 8]);
        }
        #pragma unroll
        for (int j = 0; j < 2; ++j) {
            int i = j * 256 + t;
            int row = i >> 2, seg = i & 3;
            int gseg = (seg - (row >> 1)) & 3;
            gl2lds16(Bb + ((size_t)(n0 + row) * C + kt + gseg * 8), &Bs[i * 8]);
        }
        __syncthreads();
        s16x8 af[4], bf2[4];
        #pragma unroll
        for (int mi = 0; mi < 4; ++mi) {
            int row = mc + mi * 16 + ln15;
            int sw = ((quad + (row >> 1)) & 3) << 3;
            af[mi] = *(const s16x8*)&As[row * 32 + sw];
        }
        #pragma unroll
        for (int ni = 0; ni < 4; ++ni) {
            int row = nn + ni * 16 + ln15;
            int sw = ((quad + (row >> 1)) & 3) << 3;
            bf2[ni] = *(const s16x8*)&Bs[row * 32 + sw];
        }
        #pragma unroll
        for (int mi = 0; mi < 4; ++mi)
            #pragma unroll
            for (int ni = 0; ni < 4; ++ni)
                acc[mi][ni] = MFMA_16x16x32_BF16(af[mi], bf2[ni], acc[mi][ni]);
        __syncthreads();
    }

    #pragma unroll
    for (int mi = 0; mi < 4; ++mi) {
        #pragma unroll
        for (int r = 0; r < 4; ++r) {
            int c = c0 + mc + mi * 16 + quad * 4 + r;
            float bias = bhv[c];
            size_t rowbase = ((size_t)b * C + c) * N;
            #pragma unroll
            for (int ni = 0; ni < 4; ++ni) {
                int n = n0 + nn + ni * 16 + ln15;
                HFT[rowbase + n] = __float2bfloat16(acc[mi][ni][r] + bias);
            }
        }
    }
}

// ---------------------------------------------------------------------------
// K3 v6 (k_so): FUSED S -> exp -> PV -> epilogue. P never in HBM.
//
// Round-6 post-mortem: 6225 cy/iter vs ~1700 floor with nothing busy. Two
// causes: (1) per-XCD H working set = 4 MB = EXACTLY L2 capacity -> block
// drift spills H to L3 (600+ cy latency); (2) 1 block/CU -> whole CU idles
// at every vmcnt/barrier. v6: C-SPLIT 2 BLOCKS/CU:
//   block = 64q x 256c (cb half), 256 thr / 4 waves. All blocks on one XCD
//   share the SAME 2-MB H-half (cb == xcd&1) -> guaranteed L2-resident.
//   Two independent barrier groups per CU interleave their stalls.
// Split waits (in-order vmcnt exploited): per iter issue F(i+1)[8] THEN
// H(i+1)[8]; vmcnt(24) = F(i) done -> QK overlaps H(i) stream-in;
// vmcnt(16) = H(i) done, before bar A. Wait-then-barrier = collective.
// QK+exp duplicated across the 2 c-halves (cheap: ~250 cy/CU/iter).
//
// Wave roles (4 waves): QK: (qh=w>>1, kq=w&1): S[32q x 32k] = 24 MFMA
//   (2 mi x 2 kk x 6-product split), exp, P->LDS (swz byte ^= (q&7)<<4).
// PV: wave owns c-slice w*64..+63 of the block's 256: 32 MFMA (4mi x 4ni x
//   2ks), pa from Pl, hf from Hs (pre-swizzled-source layout, T21).
// Grid 512 = 8 xcd x 64 qs: b = xcd>>1, cb = xcd&1, qs = id>>3 (bijective).
__global__ __launch_bounds__(256, 2) void k_so(const __hip_bfloat16* __restrict__ GFhi, const __hip_bfloat16* __restrict__ GFlo,
                                               const __hip_bfloat16* __restrict__ FFhi, const __hip_bfloat16* __restrict__ FFlo,
                                               const __hip_bfloat16* __restrict__ HFT,
                                               const float* __restrict__ x,
                                               const float* __restrict__ scalep,
                                               float* __restrict__ out) {
    __shared__ __align__(16) __hip_bfloat16 Hs[2][256 * 64];  // 2 x 32 KB H chunks
    __shared__ __align__(16) __hip_bfloat16 Pl[64 * 64];      // 8 KB P tile
    __shared__ float sred[4][32];
    __shared__ float rsum[64];

    int id  = blockIdx.x;
    int xcd = id & 7;                 // HW round-robins blocks over XCDs
    int b   = xcd >> 1;               // batch pinned to an XCD pair
    int cb  = xcd & 1;                // c-half: uniform per XCD -> 2MB L2 set
    int qs  = id >> 3;                // 0..63
    int q0  = qs << 6;

    int t = threadIdx.x;
    int w = t >> 6, l = t & 63;
    int ln15 = l & 15, quad = l >> 4, q8 = quad << 3;
    int qh = w >> 1, kq = w & 1;      // QK-phase wave role
    int lr = l >> 3, ls = l & 7;      // H-staging lane role

    const __hip_bfloat16* Fh = FFhi + (size_t)b * N * A;
    const __hip_bfloat16* Fl = FFlo + (size_t)b * N * A;
    const __hip_bfloat16* Hb = HFT + ((size_t)b * C + cb * 256) * N;  // block's c-half

    // G A-frags (held all kernel): rows q0+qh*32+mi*16+ln15, hi+lo
    s16x8 ah[2][2], al[2][2];
    #pragma unroll
    for (int mi = 0; mi < 2; ++mi) {
        const __hip_bfloat16* gp = GFhi + (size_t)(b * N + q0 + qh * 32 + mi * 16 + ln15) * A + q8;
        const __hip_bfloat16* lp = GFlo + (size_t)(b * N + q0 + qh * 32 + mi * 16 + ln15) * A + q8;
        ah[mi][0] = *(const s16x8*)gp; ah[mi][1] = *(const s16x8*)(gp + 32);
        al[mi][0] = *(const s16x8*)lp; al[mi][1] = *(const s16x8*)(lp + 32);
    }

    f32x4 acc[4][4];                  // O acc: 64q x 64c per wave
    #pragma unroll
    for (int mi = 0; mi < 4; ++mi)
        #pragma unroll
        for (int ni = 0; ni < 4; ++ni) acc[mi][ni] = (f32x4){0.f, 0.f, 0.f, 0.f};
    float sm[2][4] = {{0.f,0.f,0.f,0.f},{0.f,0.f,0.f,0.f}};

    // H staging (rows relative to c-half): wave w covers rows {r*32+w*8+lr}.
    // Pre-swizzled source seg (T21): LDS[c][s] holds global seg s^(c&7), c&7==lr.
    const __hip_bfloat16* hsrc0 = Hb + (size_t)(w * 8 + lr) * N + ((ls ^ lr) << 3);
    // F reg loads (asm): rows kq*32 + kk*16 + ln15, col chunk q8; hi+lo, 2 cols
    uint32_t foffk[2];
    foffk[0] = (uint32_t)(((kq * 32 + ln15) * A + q8) * 2);
    foffk[1] = (uint32_t)(((kq * 32 + 16 + ln15) * A + q8) * 2);

#define STAGE_H(BUF, KT)                                                       \
    _Pragma("unroll")                                                          \
    for (int r = 0; r < 8; ++r)                                                \
        gl2lds16(hsrc0 + (size_t)(r * 32) * N + (KT),                          \
                 &Hs[BUF][(r * 32 + w * 8) * 64]);

#define LOAD_F(FN, KTNF)                                                       \
    GLOAD(FN[0], Fh, foffk[0] + (KTNF)); GLOAD(FN[1], Fh, foffk[0] + (KTNF) + 64u); \
    GLOAD(FN[2], Fl, foffk[0] + (KTNF)); GLOAD(FN[3], Fl, foffk[0] + (KTNF) + 64u); \
    GLOAD(FN[4], Fh, foffk[1] + (KTNF)); GLOAD(FN[5], Fh, foffk[1] + (KTNF) + 64u); \
    GLOAD(FN[6], Fl, foffk[1] + (KTNF)); GLOAD(FN[7], Fl, foffk[1] + (KTNF) + 64u);

    // Prologue: iter-0 loads, F first then H (order matters for split waits)
    s16x8 fA[8], fB[8];
    LOAD_F(fA, 0u)
    STAGE_H(0, 0)

// One 64-key iteration. Issue F(i+1) then H(i+1); vmcnt(24)=F(i) ready
// (QK overlaps H(i) tail); vmcnt(16)=H(i) landed, then bar A; PV; bar B.
#define KITER(KT, BUF, FC, FN)                                                 \
    {                                                                          \
        int ktn = ((KT) + 64) & (N - 1);  /* last-iter prefetch: harmless */   \
        uint32_t ktnf = (uint32_t)(ktn << 7);                                  \
        LOAD_F(FN, ktnf)                                                       \
        STAGE_H(BUF ^ 1, ktn)                                                  \
        asm volatile("s_waitcnt vmcnt(24)" ::: "memory");                      \
        __builtin_amdgcn_sched_barrier(0);                                     \
        __builtin_amdgcn_s_setprio(1);                                         \
        _Pragma("unroll")                                                      \
        for (int mi = 0; mi < 2; ++mi)                                         \
            _Pragma("unroll")                                                  \
            for (int kk = 0; kk < 2; ++kk) {                                   \
                f32x4 s = {0.f, 0.f, 0.f, 0.f};                                \
                s = MFMA_16x16x32_BF16(ah[mi][0], FC[kk * 4 + 0], s);          \
                s = MFMA_16x16x32_BF16(ah[mi][1], FC[kk * 4 + 1], s);          \
                s = MFMA_16x16x32_BF16(al[mi][0], FC[kk * 4 + 0], s);          \
                s = MFMA_16x16x32_BF16(al[mi][1], FC[kk * 4 + 1], s);          \
                s = MFMA_16x16x32_BF16(ah[mi][0], FC[kk * 4 + 2], s);          \
                s = MFMA_16x16x32_BF16(ah[mi][1], FC[kk * 4 + 3], s);          \
                int key2 = (kq * 32 + kk * 16 + ln15) << 1;                    \
                _Pragma("unroll")                                              \
                for (int r = 0; r < 4; ++r) {                                  \
                    int q = qh * 32 + mi * 16 + quad * 4 + r;                  \
                    float p = __expf(s[r]);   /* no max shift (see header) */  \
                    __hip_bfloat16 pb = __float2bfloat16(p);                   \
                    sm[mi][r] += __bfloat162float(pb);                         \
                    *(__hip_bfloat16*)((char*)Pl + q * 128 + (key2 ^ ((q & 7) << 4))) = pb; \
                }                                                              \
            }                                                                  \
        __builtin_amdgcn_s_setprio(0);                                         \
        asm volatile("s_waitcnt lgkmcnt(0)" ::: "memory");                     \
        asm volatile("s_waitcnt vmcnt(16)" ::: "memory");                      \
        __builtin_amdgcn_sched_barrier(0);                                     \
        __builtin_amdgcn_s_barrier();     /* bar A: P + Hs[BUF] ready */       \
        __builtin_amdgcn_s_setprio(1);                                         \
        _Pragma("unroll")                                                      \
        for (int ks = 0; ks < 2; ++ks) {                                       \
            s16x8 pa[4], hf[4];                                                \
            _Pragma("unroll")                                                  \
            for (int mi = 0; mi < 4; ++mi) {                                   \
                int q = mi * 16 + ln15;                                        \
                pa[mi] = *(const s16x8*)((char*)Pl + q * 128 + ((ks * 64 + quad * 16) ^ ((q & 7) << 4))); \
            }                                                                  \
            _Pragma("unroll")                                                  \
            for (int ni = 0; ni < 4; ++ni) {                                   \
                int c = w * 64 + ni * 16 + ln15;                               \
                hf[ni] = *(const s16x8*)((char*)&Hs[BUF][0] + c * 128 + ((ks * 64 + quad * 16) ^ ((c & 7) << 4))); \
            }                                                                  \
            _Pragma("unroll")                                                  \
            for (int mi = 0; mi < 4; ++mi)                                     \
                _Pragma("unroll")                                              \
                for (int ni = 0; ni < 4; ++ni)                                 \
                    acc[mi][ni] = MFMA_16x16x32_BF16(pa[mi], hf[ni], acc[mi][ni]); \
        }                                                                      \
        __builtin_amdgcn_s_setprio(0);                                         \
        __builtin_amdgcn_sched_barrier(0);                                     \
        __builtin_amdgcn_s_barrier();     /* bar B: Pl/Hs[BUF] reusable */     \
    }

    for (int kt = 0; kt < N; kt += 128) {
        KITER(kt,      0, fA, fB)
        KITER(kt + 64, 1, fB, fA)
    }
#undef KITER
#undef STAGE_H
#undef LOAD_F

    // rowsum: lane partials -> 16-lane (key) reduce -> across kq waves via LDS
    #pragma unroll
    for (int mi = 0; mi < 2; ++mi)
        #pragma unroll
        for (int r = 0; r < 4; ++r)
            #pragma unroll
            for (int d = 1; d < 16; d <<= 1)
                sm[mi][r] += __shfl_xor(sm[mi][r], d, 64);
    if (ln15 == 0) {
        #pragma unroll
        for (int mi = 0; mi < 2; ++mi)
            #pragma unroll
            for (int r = 0; r < 4; ++r)
                sred[w][mi * 16 + quad * 4 + r] = sm[mi][r];
    }
    __syncthreads();                    // also drains the tail prefetches
    if (t < 64) {
        int hq = t >> 5, row = t & 31;
        rsum[t] = sred[hq * 2][row] + sred[hq * 2 + 1][row];
    }
    __syncthreads();

    float scv = *scalep;
    #pragma unroll
    for (int mi = 0; mi < 4; ++mi) {
        #pragma unroll
        for (int r = 0; r < 4; ++r) {
            int q = mi * 16 + quad * 4 + r;
            float srs = scv / rsum[q];
            size_t rowbase = (size_t)(b * N + q0 + q) * C + cb * 256;
            #pragma unroll
            for (int ni = 0; ni < 4; ++ni) {
                size_t idx = rowbase + w * 64 + ni * 16 + ln15;
                out[idx] = acc[mi][ni][r] * srs + x[idx];
            }
        }
    }
}

// ---------------------------------------------------------------------------
extern "C" void kernel_launch(void* const* d_in, const int* in_sizes, int n_in,
                              void* d_out, int out_size, void* d_ws, size_t ws_size,
                              hipStream_t stream) {
    const float* x   = (const float*)d_in[0];
    const float* Wf  = (const float*)d_in[1];
    const float* bfv = (const float*)d_in[2];
    const float* Wg  = (const float*)d_in[3];
    const float* bgv = (const float*)d_in[4];
    const float* Wh  = (const float*)d_in[5];
    const float* bhv = (const float*)d_in[6];
    const float* sc  = (const float*)d_in[7];
    float* out = (float*)d_out;

    char* ws = (char*)d_ws;
    size_t off = 0;
    __hip_bfloat16* FFhi = (__hip_bfloat16*)(ws + off); off += (size_t)BB * N * A * 2;   // 2 MB
    __hip_bfloat16* FFlo = (__hip_bfloat16*)(ws + off); off += (size_t)BB * N * A * 2;   // 2 MB
    __hip_bfloat16* GFhi = (__hip_bfloat16*)(ws + off); off += (size_t)BB * N * A * 2;   // 2 MB
    __hip_bfloat16* GFlo = (__hip_bfloat16*)(ws + off); off += (size_t)BB * N * A * 2;   // 2 MB
    __hip_bfloat16* HFT  = (__hip_bfloat16*)(ws + off); off += (size_t)BB * C * N * 2;   // 16 MB
    char* Pbase          = (ws + off);                  off += (size_t)BB * N * N * 2;   // 128 MB (dead; kept for XT overlay)
    off += (size_t)BB * N * 4;                                                            // (old rowsum slot, unused)
    __hip_bfloat16* WhT  = (__hip_bfloat16*)(ws + off); off += (size_t)C * C * 2;        // 512 KB
    __hip_bfloat16* WfThi = (__hip_bfloat16*)(ws + off); off += (size_t)A * C * 2;       // 64 KB
    __hip_bfloat16* WfTlo = (__hip_bfloat16*)(ws + off); off += (size_t)A * C * 2;       // 64 KB
    __hip_bfloat16* WgThi = (__hip_bfloat16*)(ws + off); off += (size_t)A * C * 2;       // 64 KB
    __hip_bfloat16* WgTlo = (__hip_bfloat16*)(ws + off); off += (size_t)A * C * 2;       // 64 KB
    // XT hi/lo [b][n][k] bf16 (16 MB each) overlay the TAIL of the old P region:
    // both are fully consumed by k_hm/k_fgm before anything else touches it.
    __hip_bfloat16* XThi = (__hip_bfloat16*)(Pbase + (size_t)BB * N * N * 2 - (size_t)BB * N * C * 2);
    __hip_bfloat16* XTlo = (__hip_bfloat16*)(Pbase + (size_t)BB * N * N * 2 - 2 * (size_t)BB * N * C * 2);

    // Wh [k=512][c=512] fp32 -> WhT [c][k] bf16
    k_trans<<<dim3(C / 64, C / 64, 1), dim3(256), 0, stream>>>(Wh, WhT, C, C);
    // X [b][k=512][n=4096] fp32 -> XThi/XTlo [b][n][k]
    k_trans2<<<dim3(N / 64, C / 64, BB), dim3(256), 0, stream>>>(x, XThi, XTlo, C, N);
    // Wf/Wg [k=512][a=64] fp32 -> [a][k] hi/lo
    k_trans2<<<dim3(A / 64, C / 64, 1), dim3(256), 0, stream>>>(Wf, WfThi, WfTlo, C, A);
    k_trans2<<<dim3(A / 64, C / 64, 1), dim3(256), 0, stream>>>(Wg, WgThi, WgTlo, C, A);
    k_hm<<<dim3(C / 128, N / 128, BB), dim3(256), 0, stream>>>(WhT, XThi, bhv, HFT);
    k_fgm<<<dim3((BB * N) / 64), dim3(256), 0, stream>>>(XThi, XTlo, WfThi, WfTlo, WgThi, WgTlo,
                                                         bfv, bgv, FFhi, FFlo, GFhi, GFlo);
    // fused S/softmax/PV/epilogue — P never touches HBM; 2 blocks/CU (c-split)
    k_so<<<dim3(BB * (N / 64) * 2), dim3(256), 0, stream>>>(GFhi, GFlo, FFhi, FFlo, HFT, x, sc, out);
}

// Round 9
// 281.734 us; speedup vs baseline: 1.1430x; 1.1430x over previous
//
#include <hip/hip_runtime.h>
#include <hip/hip_bf16.h>

// Problem constants (B,C,H,W = 4,512,64,64; A=64; N=H*W=4096)
constexpr int BB = 4;
constexpr int C  = 512;
constexpr int A  = 64;
constexpr int N  = 4096;

typedef __attribute__((ext_vector_type(8))) short s16x8;   // 8 bf16 (4 VGPRs)
typedef __attribute__((ext_vector_type(4))) float f32x4;   // 4 fp32 acc

#define MFMA_16x16x32_BF16(a, b, c) __builtin_amdgcn_mfma_f32_16x16x32_bf16((a), (b), (c), 0, 0, 0)

typedef __attribute__((address_space(3))) unsigned int lds_u32_t;
typedef const __attribute__((address_space(1))) unsigned int glb_u32_t;

__device__ __forceinline__ void gl2lds16(const void* g, void* l) {
    // async global->LDS, 16B/lane; LDS dest = wave-uniform base + lane*16
    __builtin_amdgcn_global_load_lds((glb_u32_t*)g, (lds_u32_t*)l, 16, 0, 0);
}

// Issue-pinned 16B global load (volatile asm: not sinkable, dst forced live).
// Caller owns s_waitcnt vmcnt(N) before consumption.
#define GLOAD(dst, base, off)                                                  \
    asm volatile("global_load_dwordx4 %0, %1, %2"                              \
                 : "=v"(dst) : "v"(off), "s"(base))

// ---------------------------------------------------------------------------
// K0a: transpose + fp32->bf16. src [z][K][M] fp32 -> dst [z][M][K] bf16.
__global__ __launch_bounds__(256) void k_trans(const float* __restrict__ src,
                                               __hip_bfloat16* __restrict__ dst,
                                               int K, int M) {
    __shared__ __hip_bfloat16 Ls[64][66];
    int m0 = blockIdx.x << 6, k0 = blockIdx.y << 6;
    size_t bo = (size_t)blockIdx.z * K * M;
    int t = threadIdx.x;
    int lm = t & 63, g = t >> 6;
    #pragma unroll
    for (int j = 0; j < 16; ++j) {
        int kk = j * 4 + g;
        Ls[kk][lm] = __float2bfloat16(src[bo + (size_t)(k0 + kk) * M + m0 + lm]);
    }
    __syncthreads();
    #pragma unroll
    for (int j = 0; j < 16; ++j) {
        int mm = j * 4 + g;
        dst[bo + (size_t)(m0 + mm) * K + k0 + lm] = Ls[lm][mm];
    }
}

// ---------------------------------------------------------------------------
// K0b: transpose + hi/lo bf16 split. src [z][K][M] fp32 -> dhi/dlo [z][M][K].
__global__ __launch_bounds__(256) void k_trans2(const float* __restrict__ src,
                                                __hip_bfloat16* __restrict__ dhi,
                                                __hip_bfloat16* __restrict__ dlo,
                                                int K, int M) {
    __shared__ float Ls[64][65];
    int m0 = blockIdx.x << 6, k0 = blockIdx.y << 6;
    size_t bo = (size_t)blockIdx.z * K * M;
    int t = threadIdx.x;
    int lm = t & 63, g = t >> 6;
    #pragma unroll
    for (int j = 0; j < 16; ++j) {
        int kk = j * 4 + g;
        Ls[kk][lm] = src[bo + (size_t)(k0 + kk) * M + m0 + lm];
    }
    __syncthreads();
    #pragma unroll
    for (int j = 0; j < 16; ++j) {
        int mm = j * 4 + g;
        float v = Ls[lm][mm];
        __hip_bfloat16 h = __float2bfloat16(v);
        size_t idx = bo + (size_t)(m0 + mm) * K + k0 + lm;
        dhi[idx] = h;
        dlo[idx] = __float2bfloat16(v - __bfloat162float(h));
    }
}

// ---------------------------------------------------------------------------
// K1 v2 (k_fgm): f,g convs as ONE split-precision MFMA GEMM.
__global__ __launch_bounds__(256) void k_fgm(const __hip_bfloat16* __restrict__ XThi, const __hip_bfloat16* __restrict__ XTlo,
                                             const __hip_bfloat16* __restrict__ WfThi, const __hip_bfloat16* __restrict__ WfTlo,
                                             const __hip_bfloat16* __restrict__ WgThi, const __hip_bfloat16* __restrict__ WgTlo,
                                             const float* __restrict__ bfv, const float* __restrict__ bgv,
                                             __hip_bfloat16* __restrict__ FFhi, __hip_bfloat16* __restrict__ FFlo,
                                             __hip_bfloat16* __restrict__ GFhi, __hip_bfloat16* __restrict__ GFlo) {
    __shared__ __align__(16) __hip_bfloat16 Ah[64 * 32], Al[64 * 32];    // 4+4 KB
    __shared__ __align__(16) __hip_bfloat16 Bh[128 * 32], Bl[128 * 32];  // 8+8 KB
    int r0 = blockIdx.x << 6;           // global row base (b*N+n), 0..16320
    int t = threadIdx.x;
    int w = t >> 6, l = t & 63;
    int ln15 = l & 15, quad = l >> 4;
    int mh = w & 1, nh = w >> 1;

    f32x4 acc[2][4];
    #pragma unroll
    for (int mi = 0; mi < 2; ++mi)
        #pragma unroll
        for (int ni = 0; ni < 4; ++ni) acc[mi][ni] = (f32x4){0.f, 0.f, 0.f, 0.f};

    for (int kt = 0; kt < C; kt += 32) {
        {   // A tiles: 64 rows x 32 k, hi+lo, XOR-rotation swizzled segs
            int row = t >> 2, seg = t & 3;
            int gseg = (seg - (row >> 1)) & 3;
            size_t go = (size_t)(r0 + row) * C + kt + gseg * 8;
            gl2lds16(XThi + go, &Ah[t * 8]);
            gl2lds16(XTlo + go, &Al[t * 8]);
        }
        #pragma unroll
        for (int j = 0; j < 2; ++j) {   // B tiles: rows 0-63 = WfT, 64-127 = WgT
            int i = j * 256 + t;
            int row = i >> 2, seg = i & 3;
            int gseg = (seg - (row >> 1)) & 3;
            size_t go = (size_t)(row & 63) * C + kt + gseg * 8;
            const __hip_bfloat16* bh = j ? WgThi : WfThi;
            const __hip_bfloat16* bl = j ? WgTlo : WfTlo;
            gl2lds16(bh + go, &Bh[i * 8]);
            gl2lds16(bl + go, &Bl[i * 8]);
        }
        __syncthreads();
        s16x8 afh[2], afl[2], bfh[4], bfl[4];
        #pragma unroll
        for (int mi = 0; mi < 2; ++mi) {
            int row = mh * 32 + mi * 16 + ln15;
            int sw = ((quad + (row >> 1)) & 3) << 3;
            afh[mi] = *(const s16x8*)&Ah[row * 32 + sw];
            afl[mi] = *(const s16x8*)&Al[row * 32 + sw];
        }
        #pragma unroll
        for (int ni = 0; ni < 4; ++ni) {
            int row = nh * 64 + ni * 16 + ln15;
            int sw = ((quad + (row >> 1)) & 3) << 3;
            bfh[ni] = *(const s16x8*)&Bh[row * 32 + sw];
            bfl[ni] = *(const s16x8*)&Bl[row * 32 + sw];
        }
        #pragma unroll
        for (int mi = 0; mi < 2; ++mi)
            #pragma unroll
            for (int ni = 0; ni < 4; ++ni) {
                acc[mi][ni] = MFMA_16x16x32_BF16(afh[mi], bfh[ni], acc[mi][ni]);
                acc[mi][ni] = MFMA_16x16x32_BF16(afl[mi], bfh[ni], acc[mi][ni]);
                acc[mi][ni] = MFMA_16x16x32_BF16(afh[mi], bfl[ni], acc[mi][ni]);
            }
        __syncthreads();
    }

    #pragma unroll
    for (int mi = 0; mi < 2; ++mi) {
        #pragma unroll
        for (int r = 0; r < 4; ++r) {
            size_t grow = (size_t)(r0 + mh * 32 + mi * 16 + quad * 4 + r) * A;
            #pragma unroll
            for (int ni = 0; ni < 4; ++ni) {
                int col = nh * 64 + ni * 16 + ln15;     // nh selects f vs g (wave-uniform)
                if (col < A) {
                    float v = acc[mi][ni][r] + bfv[col];
                    __hip_bfloat16 h = __float2bfloat16(v);
                    FFhi[grow + col] = h;
                    FFlo[grow + col] = __float2bfloat16(v - __bfloat162float(h));
                } else {
                    int a = col - A;
                    float v = acc[mi][ni][r] + bgv[a];
                    __hip_bfloat16 h = __float2bfloat16(v);
                    GFhi[grow + a] = h;
                    GFlo[grow + a] = __float2bfloat16(v - __bfloat162float(h));
                }
            }
        }
    }
}

// ---------------------------------------------------------------------------
// K2: h conv as bf16 MFMA GEMM. HFT[c][n] = sum_k WhT[c][k]*XT[b][n][k] + bh[c].
__global__ __launch_bounds__(256) void k_hm(const __hip_bfloat16* __restrict__ WhT,
                                            const __hip_bfloat16* __restrict__ XT,
                                            const float* __restrict__ bhv,
                                            __hip_bfloat16* __restrict__ HFT) {
    __shared__ __align__(16) __hip_bfloat16 As[128 * 32];
    __shared__ __align__(16) __hip_bfloat16 Bs[128 * 32];
    int b  = blockIdx.z;
    int c0 = blockIdx.x << 7;
    int n0 = blockIdx.y << 7;
    int t = threadIdx.x;
    int w = t >> 6, l = t & 63;
    int ln15 = l & 15, quad = l >> 4;
    int mc = (w >> 1) << 6, nn = (w & 1) << 6;

    const __hip_bfloat16* Bb = XT + (size_t)b * N * C;   // [4096, 512]

    f32x4 acc[4][4];
    #pragma unroll
    for (int mi = 0; mi < 4; ++mi)
        #pragma unroll
        for (int ni = 0; ni < 4; ++ni) acc[mi][ni] = (f32x4){0.f, 0.f, 0.f, 0.f};

    for (int kt = 0; kt < C; kt += 32) {
        #pragma unroll
        for (int j = 0; j < 2; ++j) {
            int i = j * 256 + t;
            int row = i >> 2, seg = i & 3;
            int gseg = (seg - (row >> 1)) & 3;
            gl2lds16(WhT + ((size_t)(c0 + row) * C + kt + gseg * 8), &As[i * 8]);
        }
        #pragma unroll
        for (int j = 0; j < 2; ++j) {
            int i = j * 256 + t;
            int row = i >> 2, seg = i & 3;
            int gseg = (seg - (row >> 1)) & 3;
            gl2lds16(Bb + ((size_t)(n0 + row) * C + kt + gseg * 8), &Bs[i * 8]);
        }
        __syncthreads();
        s16x8 af[4], bf2[4];
        #pragma unroll
        for (int mi = 0; mi < 4; ++mi) {
            int row = mc + mi * 16 + ln15;
            int sw = ((quad + (row >> 1)) & 3) << 3;
            af[mi] = *(const s16x8*)&As[row * 32 + sw];
        }
        #pragma unroll
        for (int ni = 0; ni < 4; ++ni) {
            int row = nn + ni * 16 + ln15;
            int sw = ((quad + (row >> 1)) & 3) << 3;
            bf2[ni] = *(const s16x8*)&Bs[row * 32 + sw];
        }
        #pragma unroll
        for (int mi = 0; mi < 4; ++mi)
            #pragma unroll
            for (int ni = 0; ni < 4; ++ni)
                acc[mi][ni] = MFMA_16x16x32_BF16(af[mi], bf2[ni], acc[mi][ni]);
        __syncthreads();
    }

    #pragma unroll
    for (int mi = 0; mi < 4; ++mi) {
        #pragma unroll
        for (int r = 0; r < 4; ++r) {
            int c = c0 + mc + mi * 16 + quad * 4 + r;
            float bias = bhv[c];
            size_t rowbase = ((size_t)b * C + c) * N;
            #pragma unroll
            for (int ni = 0; ni < 4; ++ni) {
                int n = n0 + nn + ni * 16 + ln15;
                HFT[rowbase + n] = __float2bfloat16(acc[mi][ni][r] + bias);
            }
        }
    }
}

// ---------------------------------------------------------------------------
// K3 v7 (k_so): FUSED S -> exp -> PV -> epilogue. P never in HBM.
// (Round-8 bench died in infra before any dispatch — same signature as
// round 5, which a byte-identical resubmit then passed. Static re-audit:
// vmcnt ledger exact, barriers uniform, no OOB. Resubmitted unchanged.)
//
// Round-7 post-mortem: 3 memory mechanisms (reg prefetch / LDS-DMA 1-blk /
// LDS-DMA 2-blk) all stuck ~25% MfmaUtil -> the invariant is the SCHEDULE:
// QK(i)->barA->PV(i)->barB lockstep leaves the intra-iteration QK->P->PV
// dependency on the critical path with nothing to overlap it. v7 SOFTWARE-
// PIPELINES QK one iteration ahead: body i = { QK(i+1)->Pl[1-b]  ||
// PV(i)<-Pl[b],Hs[b] } — two INDEPENDENT groups between barriers (44 MFMA +
// exp with full ILP), ONE barrier per body (WAR on Pl/Hs protected by the
// NEXT barrier). Shape reverted to v5 (best measured): 8 waves, 64q x 512c,
// grid 256 = 1 block/CU.
// Loads per body: STAGE_H(i+1)[8 DMA] then GLOAD F(i+2)[4] at body start;
//   vmcnt(12) before QK  = F(i+1) retired (H(i+1),F(i+2) in flight);
//   vmcnt(4) before bar  = H(i+1) landed (F(i+2) crosses the barrier).
// Steady state: 4 ops in flight at body entry; every load gets a full body
// (~1500+ cy) of latency cover.
// P_lds swizzle byte ^= (q&7)<<4 (verified v5); Hs via pre-swizzled source.
__global__ __launch_bounds__(512, 2) void k_so(const __hip_bfloat16* __restrict__ GFhi, const __hip_bfloat16* __restrict__ GFlo,
                                               const __hip_bfloat16* __restrict__ FFhi, const __hip_bfloat16* __restrict__ FFlo,
                                               const __hip_bfloat16* __restrict__ HFT,
                                               const float* __restrict__ x,
                                               const float* __restrict__ scalep,
                                               float* __restrict__ out) {
    __shared__ __align__(16) __hip_bfloat16 Hs[2][C * 64];   // 2 x 64 KB H chunks
    __shared__ __align__(16) __hip_bfloat16 Pl[2][64 * 64];  // 2 x 8 KB P tiles
    __shared__ float sred[8][32];
    __shared__ float rsum[64];

    int id  = blockIdx.x;
    int xcd = id & 7;                         // HW round-robins blocks over XCDs
    int b   = xcd >> 1;                       // batch pinned to an XCD pair
    int qs  = ((id >> 3) << 1) | (xcd & 1);   // 0..63, bijective with id
    int q0  = qs << 6;

    int t = threadIdx.x;
    int w = t >> 6, l = t & 63;
    int ln15 = l & 15, quad = l >> 4, q8 = quad << 3;
    int qh = w >> 2, kq = w & 3;              // QK-phase wave role
    int lr = l >> 3, ls = l & 7;              // H-staging lane role

    const __hip_bfloat16* Fh = FFhi + (size_t)b * N * A;
    const __hip_bfloat16* Fl = FFlo + (size_t)b * N * A;
    const __hip_bfloat16* Hb = HFT  + (size_t)b * C * N;

    // G A-frags (held all kernel): rows q0+qh*32+mi*16+ln15, hi+lo
    s16x8 ah[2][2], al[2][2];
    #pragma unroll
    for (int mi = 0; mi < 2; ++mi) {
        const __hip_bfloat16* gp = GFhi + (size_t)(b * N + q0 + qh * 32 + mi * 16 + ln15) * A + q8;
        const __hip_bfloat16* lp = GFlo + (size_t)(b * N + q0 + qh * 32 + mi * 16 + ln15) * A + q8;
        ah[mi][0] = *(const s16x8*)gp; ah[mi][1] = *(const s16x8*)(gp + 32);
        al[mi][0] = *(const s16x8*)lp; al[mi][1] = *(const s16x8*)(lp + 32);
    }

    f32x4 acc[4][4];                            // O acc: 64q x 64c per wave
    #pragma unroll
    for (int mi = 0; mi < 4; ++mi)
        #pragma unroll
        for (int ni = 0; ni < 4; ++ni) acc[mi][ni] = (f32x4){0.f, 0.f, 0.f, 0.f};
    float sm[2][4] = {{0.f,0.f,0.f,0.f},{0.f,0.f,0.f,0.f}};

    // H staging: round r stages rows r*64+w*8+lr; seg ls holds global seg ls^lr
    // (pre-swizzled source, T21; read applies the same XOR).
    const __hip_bfloat16* hsrc0 = Hb + (size_t)(w * 8 + lr) * N + ((ls ^ lr) << 3);
    // F reg loads (asm): row kq*16+ln15, col chunk q8
    uint32_t foff = (uint32_t)(((kq * 16 + ln15) * A + q8) * 2);
    int key2 = (kq * 16 + ln15) << 1;           // P byte column for QK store

#define STAGE_H(BUF, KT)                                                       \
    _Pragma("unroll")                                                          \
    for (int r = 0; r < 8; ++r)                                                \
        gl2lds16(hsrc0 + (size_t)(r * 64) * N + (KT),                          \
                 &Hs[BUF][(r * 64 + w * 8) * 64]);

#define LOAD_F(FN, KTF)                                                        \
    GLOAD(FN[0], Fh, foff + (KTF));      GLOAD(FN[1], Fh, foff + (KTF) + 64u); \
    GLOAD(FN[2], Fl, foff + (KTF));      GLOAD(FN[3], Fl, foff + (KTF) + 64u);

// QK for the NEXT chunk: 12 MFMA + exp, P -> Pl[PW]
#define QK_STEP(PW, FC)                                                        \
    _Pragma("unroll")                                                          \
    for (int mi = 0; mi < 2; ++mi) {                                           \
        f32x4 s = {0.f, 0.f, 0.f, 0.f};                                        \
        s = MFMA_16x16x32_BF16(ah[mi][0], FC[0], s);                           \
        s = MFMA_16x16x32_BF16(ah[mi][1], FC[1], s);                           \
        s = MFMA_16x16x32_BF16(al[mi][0], FC[0], s);                           \
        s = MFMA_16x16x32_BF16(al[mi][1], FC[1], s);                           \
        s = MFMA_16x16x32_BF16(ah[mi][0], FC[2], s);                           \
        s = MFMA_16x16x32_BF16(ah[mi][1], FC[3], s);                           \
        _Pragma("unroll")                                                      \
        for (int r = 0; r < 4; ++r) {                                          \
            int q = qh * 32 + mi * 16 + quad * 4 + r;                          \
            float p = __expf(s[r]);           /* no max shift (see header) */  \
            __hip_bfloat16 pb = __float2bfloat16(p);                           \
            sm[mi][r] += __bfloat162float(pb);                                 \
            *(__hip_bfloat16*)((char*)&Pl[PW][0] + q * 128 + (key2 ^ ((q & 7) << 4))) = pb; \
        }                                                                      \
    }

// PV for the CURRENT chunk: 16 LDS b128 reads + 32 MFMA
#define PV_STEP(PR, HR)                                                        \
    _Pragma("unroll")                                                          \
    for (int ks = 0; ks < 2; ++ks) {                                           \
        s16x8 pa[4], hf[4];                                                    \
        _Pragma("unroll")                                                      \
        for (int mi = 0; mi < 4; ++mi) {                                       \
            int q = mi * 16 + ln15;                                            \
            pa[mi] = *(const s16x8*)((char*)&Pl[PR][0] + q * 128 + ((ks * 64 + quad * 16) ^ ((q & 7) << 4))); \
        }                                                                      \
        _Pragma("unroll")                                                      \
        for (int ni = 0; ni < 4; ++ni) {                                       \
            int c = w * 64 + ni * 16 + ln15;                                   \
            hf[ni] = *(const s16x8*)((char*)&Hs[HR][0] + c * 128 + (((ks * 4 + quad) ^ (ln15 & 7)) << 4)); \
        }                                                                      \
        _Pragma("unroll")                                                      \
        for (int mi = 0; mi < 4; ++mi)                                         \
            _Pragma("unroll")                                                  \
            for (int ni = 0; ni < 4; ++ni)                                     \
                acc[mi][ni] = MFMA_16x16x32_BF16(pa[mi], hf[ni], acc[mi][ni]); \
    }

// Body i (KT = i*64): stage H(i+1)->Hs[HW], load F(i+2)->FN; QK(i+1)->Pl[PW]
// || PV(i)<-Pl[PR],Hs[HR]; one barrier.
#define KBODY(KT, HW, HR, PW, PR, FC, FN)                                      \
    {                                                                          \
        int ktn1 = (KT) + 64;                                                  \
        int ktn2 = ((KT) + 128) & (N - 1);    /* wrap: last loads unused */    \
        STAGE_H(HW, ktn1)                                                      \
        LOAD_F(FN, (uint32_t)(ktn2 << 7))                                      \
        asm volatile("s_waitcnt vmcnt(12)" ::: "memory");  /* F(i+1) ready */  \
        __builtin_amdgcn_sched_barrier(0);                                     \
        __builtin_amdgcn_s_setprio(1);                                         \
        QK_STEP(PW, FC)                                                        \
        PV_STEP(PR, HR)                                                        \
        __builtin_amdgcn_s_setprio(0);                                         \
        asm volatile("s_waitcnt vmcnt(4)" ::: "memory");   /* H(i+1) landed */ \
        asm volatile("s_waitcnt lgkmcnt(0)" ::: "memory"); /* P writes done */ \
        __builtin_amdgcn_sched_barrier(0);                                     \
        __builtin_amdgcn_s_barrier();                                          \
    }

    // ---- Prologue: F(0), H(0), F(1); QK(0) -> Pl[0]; barrier.
    s16x8 fA[4], fB[4];
    LOAD_F(fA, 0u)
    STAGE_H(0, 0)
    LOAD_F(fB, (uint32_t)(64 << 7))
    asm volatile("s_waitcnt vmcnt(12)" ::: "memory");      // F(0) ready
    __builtin_amdgcn_sched_barrier(0);
    QK_STEP(0, fA)
    asm volatile("s_waitcnt vmcnt(4)" ::: "memory");       // H(0) landed
    asm volatile("s_waitcnt lgkmcnt(0)" ::: "memory");
    __builtin_amdgcn_sched_barrier(0);
    __builtin_amdgcn_s_barrier();

    // ---- 63 pipelined bodies (31 pairs + 1), then PV(63) epilogue.
    int kt = 0;
    for (int it = 0; it < 31; ++it) {
        KBODY(kt,      1, 0, 1, 0, fB, fA)   // even body
        KBODY(kt + 64, 0, 1, 0, 1, fA, fB)   // odd body
        kt += 128;
    }
    KBODY(kt, 1, 0, 1, 0, fB, fA)            // body 62 (kt = 3968)
    __builtin_amdgcn_s_setprio(1);
    PV_STEP(1, 1)                            // PV(63)
    __builtin_amdgcn_s_setprio(0);

#undef KBODY
#undef PV_STEP
#undef QK_STEP
#undef LOAD_F
#undef STAGE_H

    // rowsum: lane partials -> 16-lane (key) reduce -> across kq waves via LDS
    #pragma unroll
    for (int mi = 0; mi < 2; ++mi)
        #pragma unroll
        for (int r = 0; r < 4; ++r)
            #pragma unroll
            for (int d = 1; d < 16; d <<= 1)
                sm[mi][r] += __shfl_xor(sm[mi][r], d, 64);
    if (ln15 == 0) {
        #pragma unroll
        for (int mi = 0; mi < 2; ++mi)
            #pragma unroll
            for (int r = 0; r < 4; ++r)
                sred[w][mi * 16 + quad * 4 + r] = sm[mi][r];
    }
    __syncthreads();                    // also drains the tail prefetches
    if (t < 64) {
        int base = (t >> 5) << 2, ix = t & 31;
        rsum[t] = sred[base][ix] + sred[base + 1][ix] + sred[base + 2][ix] + sred[base + 3][ix];
    }
    __syncthreads();

    float scv = *scalep;
    #pragma unroll
    for (int mi = 0; mi < 4; ++mi) {
        #pragma unroll
        for (int r = 0; r < 4; ++r) {
            int q = mi * 16 + quad * 4 + r;
            float srs = scv / rsum[q];
            size_t rowbase = (size_t)(b * N + q0 + q) * C;
            #pragma unroll
            for (int ni = 0; ni < 4; ++ni) {
                size_t idx = rowbase + w * 64 + ni * 16 + ln15;
                out[idx] = acc[mi][ni][r] * srs + x[idx];
            }
        }
    }
}

// ---------------------------------------------------------------------------
extern "C" void kernel_launch(void* const* d_in, const int* in_sizes, int n_in,
                              void* d_out, int out_size, void* d_ws, size_t ws_size,
                              hipStream_t stream) {
    const float* x   = (const float*)d_in[0];
    const float* Wf  = (const float*)d_in[1];
    const float* bfv = (const float*)d_in[2];
    const float* Wg  = (const float*)d_in[3];
    const float* bgv = (const float*)d_in[4];
    const float* Wh  = (const float*)d_in[5];
    const float* bhv = (const float*)d_in[6];
    const float* sc  = (const float*)d_in[7];
    float* out = (float*)d_out;

    char* ws = (char*)d_ws;
    size_t off = 0;
    __hip_bfloat16* FFhi = (__hip_bfloat16*)(ws + off); off += (size_t)BB * N * A * 2;   // 2 MB
    __hip_bfloat16* FFlo = (__hip_bfloat16*)(ws + off); off += (size_t)BB * N * A * 2;   // 2 MB
    __hip_bfloat16* GFhi = (__hip_bfloat16*)(ws + off); off += (size_t)BB * N * A * 2;   // 2 MB
    __hip_bfloat16* GFlo = (__hip_bfloat16*)(ws + off); off += (size_t)BB * N * A * 2;   // 2 MB
    __hip_bfloat16* HFT  = (__hip_bfloat16*)(ws + off); off += (size_t)BB * C * N * 2;   // 16 MB
    char* Pbase          = (ws + off);                  off += (size_t)BB * N * N * 2;   // 128 MB (dead; kept for XT overlay)
    off += (size_t)BB * N * 4;                                                            // (old rowsum slot, unused)
    __hip_bfloat16* WhT  = (__hip_bfloat16*)(ws + off); off += (size_t)C * C * 2;        // 512 KB
    __hip_bfloat16* WfThi = (__hip_bfloat16*)(ws + off); off += (size_t)A * C * 2;       // 64 KB
    __hip_bfloat16* WfTlo = (__hip_bfloat16*)(ws + off); off += (size_t)A * C * 2;       // 64 KB
    __hip_bfloat16* WgThi = (__hip_bfloat16*)(ws + off); off += (size_t)A * C * 2;       // 64 KB
    __hip_bfloat16* WgTlo = (__hip_bfloat16*)(ws + off); off += (size_t)A * C * 2;       // 64 KB
    // XT hi/lo [b][n][k] bf16 (16 MB each) overlay the TAIL of the old P region:
    // both are fully consumed by k_hm/k_fgm before anything else touches it.
    __hip_bfloat16* XThi = (__hip_bfloat16*)(Pbase + (size_t)BB * N * N * 2 - (size_t)BB * N * C * 2);
    __hip_bfloat16* XTlo = (__hip_bfloat16*)(Pbase + (size_t)BB * N * N * 2 - 2 * (size_t)BB * N * C * 2);

    // Wh [k=512][c=512] fp32 -> WhT [c][k] bf16
    k_trans<<<dim3(C / 64, C / 64, 1), dim3(256), 0, stream>>>(Wh, WhT, C, C);
    // X [b][k=512][n=4096] fp32 -> XThi/XTlo [b][n][k]
    k_trans2<<<dim3(N / 64, C / 64, BB), dim3(256), 0, stream>>>(x, XThi, XTlo, C, N);
    // Wf/Wg [k=512][a=64] fp32 -> [a][k] hi/lo
    k_trans2<<<dim3(A / 64, C / 64, 1), dim3(256), 0, stream>>>(Wf, WfThi, WfTlo, C, A);
    k_trans2<<<dim3(A / 64, C / 64, 1), dim3(256), 0, stream>>>(Wg, WgThi, WgTlo, C, A);
    k_hm<<<dim3(C / 128, N / 128, BB), dim3(256), 0, stream>>>(WhT, XThi, bhv, HFT);
    k_fgm<<<dim3((BB * N) / 64), dim3(256), 0, stream>>>(XThi, XTlo, WfThi, WfTlo, WgThi, WgTlo,
                                                         bfv, bgv, FFhi, FFlo, GFhi, GFlo);
    // fused S/softmax/PV/epilogue — P never touches HBM; 1-barrier pipelined
    k_so<<<dim3(BB * (N / 64)), dim3(512), 0, stream>>>(GFhi, GFlo, FFhi, FFlo, HFT, x, sc, out);
}